// Round 7
// baseline (499.935 us; speedup 1.0000x reference)
//
#include <hip/hip_runtime.h>
#include <hip/hip_fp16.h>

#define NN 50000
#define NE 800000
// IN_C=16, EDGE_IN=16, HID=32, HEADS=4, HC=128
#define NB 196            // coarse buckets = ceil(NN/256)
#define EPB 3125          // edges per bucket-build block (NE/256)
#define NODE_BLOCKS 12500 // NN/4

// scale folded into all alpha components: log2(e)/sqrt(32)
#define SL 0.25506413f

// packed-table offsets (floats) inside P
#define P_M    0      // 1024: M[h][i][j] pre-scaled
#define P_BQK  1024   // 4
#define P_WP   1040   // 4096: per-lane {We_lo, We_hi, Wv_lo, Wv_hi} x16
#define P_WSP  5136   // 512:  per-t {Wskip pairs} x8
#define P_W1P  5648   // 2048: per-lane W1 A/C columns x8
#define P_W1EP 7696   // 512:  per-l W1 edge columns x4
#define P_TOTAL 8208

template <int CTRL>
__device__ __forceinline__ float dpp_add(float v) {
  int m = __builtin_amdgcn_update_dpp(0, __builtin_bit_cast(int, v), CTRL, 0xF, 0xF, true);
  return v + __builtin_bit_cast(float, m);
}
// quad xor1=0xB1, quad xor2=0x4E, row_ror:4=0x124, row_ror:8=0x128

// ---------------- Kernel 0: weight precompute --------------------------
__global__ __launch_bounds__(256) void precompute_kernel(
    const float* __restrict__ Wq, const float* __restrict__ Wk,
    const float* __restrict__ bq, const float* __restrict__ bk,
    const float* __restrict__ We, const float* __restrict__ Wv,
    const float* __restrict__ Wskip, const float* __restrict__ W1,
    float* __restrict__ P) {
  int t = threadIdx.x;
  for (int idx = t; idx < 1024; idx += 256) {
    int h = idx >> 8, i = (idx >> 4) & 15, j = idx & 15;
    float acc = 0.f;
#pragma unroll
    for (int c = 0; c < 32; c++)
      acc += Wq[i * 128 + h * 32 + c] * Wk[j * 128 + h * 32 + c];
    P[P_M + idx] = acc * SL;
  }
  if (t < 4) {
    float acc = 0.f;
#pragma unroll
    for (int c = 0; c < 32; c++) acc += bq[t * 32 + c] * bk[t * 32 + c];
    P[P_BQK + t] = acc * SL;
  }
  // WP: lane=(h,t16), i -> {We[i][h*32+t], We[i][h*32+16+t], Wv same}
  for (int idx = t; idx < 1024; idx += 256) {
    int lane = idx >> 4, i = idx & 15;
    int h = lane >> 4, tt = lane & 15;
    float4 v;
    v.x = We[i * 128 + h * 32 + tt];
    v.y = We[i * 128 + h * 32 + 16 + tt];
    v.z = Wv[i * 128 + h * 32 + tt];
    v.w = Wv[i * 128 + h * 32 + 16 + tt];
    ((float4*)(P + P_WP))[idx] = v;
  }
  // WSP: per t16, k=0..7 -> {Wskip[2k][t], Wskip[2k][t+16], Wskip[2k+1][t], Wskip[2k+1][t+16]}
  for (int idx = t; idx < 128; idx += 256) {
    int tt = idx >> 3, k = idx & 7;
    float4 v;
    v.x = Wskip[(2 * k) * 32 + tt];
    v.y = Wskip[(2 * k) * 32 + tt + 16];
    v.z = Wskip[(2 * k + 1) * 32 + tt];
    v.w = Wskip[(2 * k + 1) * 32 + tt + 16];
    ((float4*)(P + P_WSP))[idx] = v;
  }
  // W1P: per lane, k=0..7: rows roff+(k>=4?16:0)+4*(k&3) .. +3, col jj
  for (int idx = t; idx < 512; idx += 256) {
    int lane = idx >> 3, k = idx & 7;
    int jj = lane & 31;
    int r = ((lane < 32) ? 0 : 48) + ((k >= 4) ? 16 : 0) + 4 * (k & 3);
    float4 v;
    v.x = W1[(r + 0) * 32 + jj];
    v.y = W1[(r + 1) * 32 + jj];
    v.z = W1[(r + 2) * 32 + jj];
    v.w = W1[(r + 3) * 32 + jj];
    ((float4*)(P + P_W1P))[idx] = v;
  }
  // W1EP: per l (0..31), k=0..3: rows 32+4k..+3, col l
  for (int idx = t; idx < 128; idx += 256) {
    int l = idx >> 2, k = idx & 3;
    float4 v;
    v.x = W1[(32 + 4 * k + 0) * 32 + l];
    v.y = W1[(32 + 4 * k + 1) * 32 + l];
    v.z = W1[(32 + 4 * k + 2) * 32 + l];
    v.w = W1[(32 + 4 * k + 3) * 32 + l];
    ((float4*)(P + P_W1EP))[idx] = v;
  }
}

// ---------------- Kernel 1: node precompute + coarse hist (fused) ------
__global__ __launch_bounds__(256) void node_linear_kernel(
    const float* __restrict__ x,
    const float* __restrict__ Wq, const float* __restrict__ bq,
    const float* __restrict__ Wk, const float* __restrict__ bk,
    const float* __restrict__ We, const float* __restrict__ P,
    const int* __restrict__ ei, int* __restrict__ hist_all,
    float* __restrict__ y, float* __restrict__ qe,
    float* __restrict__ u4, float* __restrict__ w4) {
  __shared__ int hist[NB];
  if (blockIdx.x >= NODE_BLOCKS) {
    int b = blockIdx.x - NODE_BLOCKS;  // [0,256)
    int t = threadIdx.x;
    if (t < NB) hist[t] = 0;
    __syncthreads();
    int base = b * EPB;
    for (int i = t; i < EPB; i += 256)
      atomicAdd(&hist[ei[NE + base + i] >> 8], 1);
    __syncthreads();
    if (t < NB) hist_all[t * 256 + b] = hist[t];
    return;
  }
  int wave = threadIdx.x >> 6;
  int lane = threadIdx.x & 63;
  int n = blockIdx.x * 4 + wave;
  int h = lane >> 4, t = lane & 15, base = h * 32 + t;
  int gb = lane & 48;

  float xr[16];
#pragma unroll
  for (int i = 0; i < 16; i++) xr[i] = x[n * 16 + i];

  float bqb = bq[base], bq16 = bq[base + 16];
  float bkb = bk[base], bk16 = bk[base + 16];
  float qb = bqb, q16 = bq16;
  float kb = bkb, k16 = bk16;
#pragma unroll
  for (int i = 0; i < 16; i++) {
    qb  += xr[i] * Wq[i * 128 + base];
    q16 += xr[i] * Wq[i * 128 + base + 16];
    kb  += xr[i] * Wk[i * 128 + base];
    k16 += xr[i] * Wk[i * 128 + base + 16];
  }

  // y_ht = sum_i x_i * M[h][i][t]  (pre-scaled)
  float yt = 0.f;
#pragma unroll
  for (int i = 0; i < 16; i++) yt += xr[i] * P[P_M + h * 256 + i * 16 + t];
  y[n * 64 + lane] = yt;

  // qe[h][t] = SL * sum_c q[h*32+c] * We[t*128 + h*32 + c]
  float acc = 0.f;
#pragma unroll
  for (int i = 0; i < 16; i++) {
    float qv  = __shfl(qb,  gb | i);
    float qv2 = __shfl(q16, gb | i);
    acc += qv * We[t * 128 + h * 32 + i] + qv2 * We[t * 128 + h * 32 + 16 + i];
  }
  qe[n * 64 + lane] = acc * SL;

  // u_h, w_h
  float pu = qb * bkb + q16 * bk16;
  float pw = bqb * kb + bq16 * k16;
  pu += __shfl_xor(pu, 1); pw += __shfl_xor(pw, 1);
  pu += __shfl_xor(pu, 2); pw += __shfl_xor(pw, 2);
  pu += __shfl_xor(pu, 4); pw += __shfl_xor(pw, 4);
  pu += __shfl_xor(pu, 8); pw += __shfl_xor(pw, 8);
  if (t == 0) {
    u4[n * 4 + h] = pu * SL - P[P_BQK + h];
    w4[n * 4 + h] = pw * SL;
  }
}

// ---------------- CSR build ---------------------------------------------
__global__ __launch_bounds__(256) void scan_buckets_kernel(
    int* __restrict__ hist_all, int* __restrict__ btot) {
  int wv = blockIdx.x * 4 + (threadIdx.x >> 6);
  int l = threadIdx.x & 63;
  if (wv >= NB) return;
  int base = wv * 256;
  int run = 0;
#pragma unroll
  for (int c = 0; c < 4; c++) {
    int v = hist_all[base + c * 64 + l];
    int orig = v;
#pragma unroll
    for (int d = 1; d < 64; d <<= 1) {
      int u = __shfl_up(v, d);
      if (l >= d) v += u;
    }
    hist_all[base + c * 64 + l] = run + v - orig;
    run += __shfl(v, 63);
  }
  if (l == 0) btot[wv] = run;
}

__global__ __launch_bounds__(256) void tiny_scan_kernel(
    const int* __restrict__ btot, int* __restrict__ coarse_offs) {
  __shared__ int sc[256];
  int t = threadIdx.x;
  int v = (t < NB) ? btot[t] : 0;
  sc[t] = v;
  __syncthreads();
  for (int d = 1; d < 256; d <<= 1) {
    int u = (t >= d) ? sc[t - d] : 0;
    __syncthreads();
    sc[t] += u;
    __syncthreads();
  }
  if (t < NB) coarse_offs[t] = sc[t] - v;
  if (t == NB - 1) coarse_offs[NB] = sc[t];
}

__global__ __launch_bounds__(256) void bucket_scatter_kernel(
    const int* __restrict__ ei, const int* __restrict__ cursor_all,
    const int* __restrict__ coarse_offs, int2* __restrict__ s_tmp) {
  __shared__ int cur[NB];
  int t = threadIdx.x, b = blockIdx.x;
  if (t < NB) cur[t] = cursor_all[t * 256 + b] + coarse_offs[t];
  __syncthreads();
  int base = b * EPB;
  for (int i = t; i < EPB; i += 256) {
    int e = base + i;
    int src = ei[e], dst = ei[NE + e];
    int pos = atomicAdd(&cur[dst >> 8], 1);
    s_tmp[pos] = make_int2(src | ((dst & 255) << 16), e);
  }
}

__global__ __launch_bounds__(256) void fine_csr_kernel(
    const int2* __restrict__ s_tmp, const int* __restrict__ coarse_offs,
    int* __restrict__ s_src, int* __restrict__ s_eid, int* __restrict__ offs) {
  __shared__ int cnt[256], sc[256], cur[256];
  int t = threadIdx.x, b = blockIdx.x;
  int lo = coarse_offs[b], hi = coarse_offs[b + 1];
  cnt[t] = 0;
  __syncthreads();
  for (int p = lo + t; p < hi; p += 256)
    atomicAdd(&cnt[(s_tmp[p].x >> 16) & 255], 1);
  __syncthreads();
  int myc = cnt[t];
  sc[t] = myc;
  __syncthreads();
  for (int d = 1; d < 256; d <<= 1) {
    int v = (t >= d) ? sc[t - d] : 0;
    __syncthreads();
    sc[t] += v;
    __syncthreads();
  }
  int excl = sc[t] - myc;
  cur[t] = lo + excl;
  int gd = b * 256 + t;
  if (gd <= NN) offs[gd] = lo + excl;
  __syncthreads();
  for (int p = lo + t; p < hi; p += 256) {
    int2 w = s_tmp[p];
    int pos = atomicAdd(&cur[(w.x >> 16) & 255], 1);
    s_src[pos] = w.x & 0xFFFF;
    s_eid[pos] = w.y;
  }
}

// ---------------- Kernel 2b: permute edge_attr to CSR order as f16 -----
__global__ __launch_bounds__(256) void perm_ea_kernel(
    const int* __restrict__ s_eid, const float* __restrict__ edge_attr,
    __half* __restrict__ s_ea) {
  int idx = blockIdx.x * 256 + threadIdx.x;  // NE*4 lanes
  int e = idx >> 2, m = idx & 3;
  int eid = s_eid[e];
  float4 v = *(const float4*)(edge_attr + (size_t)eid * 16 + m * 4);
  __half2 h0 = __floats2half2_rn(v.x, v.y);
  __half2 h1 = __floats2half2_rn(v.z, v.w);
  uint2 pk;
  pk.x = *(unsigned*)&h0;
  pk.y = *(unsigned*)&h1;
  *(uint2*)(s_ea + (size_t)e * 16 + m * 4) = pk;
}

// ---------------- Kernel 3: aggregation + A/C epilogue -----------------
// lane = (h, e'=edge-slot, t4); 4 edges/iter; quad-DPP dot reduce.
__global__ __launch_bounds__(256) void aggregate_kernel(
    const float* __restrict__ y, const float* __restrict__ qe,
    const float* __restrict__ u4, const float* __restrict__ w4,
    const float* __restrict__ x, const __half* __restrict__ s_ea,
    const int* __restrict__ s_src, const int* __restrict__ offs,
    const float* __restrict__ bv, const float* __restrict__ bskip,
    const float* __restrict__ b1, const float* __restrict__ P,
    float* __restrict__ A, float* __restrict__ Cb) {
  int wave = threadIdx.x >> 6, lane = threadIdx.x & 63;
  int n = blockIdx.x * 4 + wave;
  if (n >= NN) return;
  int h = lane >> 4;
  int e4 = (lane >> 2) & 3;
  int t4 = lane & 3;

  float4 y4 = ((const float4*)(y + n * 64))[h * 4 + t4];
  float4 q4 = ((const float4*)(qe + n * 64))[h * 4 + t4];
  float u_n = u4[n * 4 + h];
  int off = offs[n], end = offs[n + 1];

  float s = 0.f;
  float ax0 = 0.f, ax1 = 0.f, ax2 = 0.f, ax3 = 0.f;
  float ae0 = 0.f, ae1 = 0.f, ae2 = 0.f, ae3 = 0.f;
  int j = off;
  for (; j + 4 <= end; j += 4) {
    int srcu = s_src[j + e4];
    float4 xv = *(const float4*)(x + (size_t)srcu * 16 + t4 * 4);
    uint2 eah = *(const uint2*)(s_ea + (size_t)(j + e4) * 16 + t4 * 4);
    float2 ea01 = __half22float2(*(const __half2*)&eah.x);
    float2 ea23 = __half22float2(*(const __half2*)&eah.y);
    float w4v = w4[srcu * 4 + h];
    float p = y4.x * xv.x + y4.y * xv.y + y4.z * xv.z + y4.w * xv.w
            + q4.x * ea01.x + q4.y * ea01.y + q4.z * ea23.x + q4.w * ea23.y;
    p = dpp_add<0xB1>(p);
    p = dpp_add<0x4E>(p);
    float wgt = exp2f(p + u_n + w4v);
    s += wgt;
    ax0 += wgt * xv.x; ax1 += wgt * xv.y; ax2 += wgt * xv.z; ax3 += wgt * xv.w;
    ae0 += wgt * ea01.x; ae1 += wgt * ea01.y; ae2 += wgt * ea23.x; ae3 += wgt * ea23.y;
  }
  if (j < end) {  // predicated parallel tail (1..3 edges)
    int je = j + e4;
    bool valid = je < end;
    int jc = valid ? je : end - 1;
    int srcu = s_src[jc];
    float4 xv = *(const float4*)(x + (size_t)srcu * 16 + t4 * 4);
    uint2 eah = *(const uint2*)(s_ea + (size_t)jc * 16 + t4 * 4);
    float2 ea01 = __half22float2(*(const __half2*)&eah.x);
    float2 ea23 = __half22float2(*(const __half2*)&eah.y);
    float w4v = w4[srcu * 4 + h];
    float p = y4.x * xv.x + y4.y * xv.y + y4.z * xv.z + y4.w * xv.w
            + q4.x * ea01.x + q4.y * ea01.y + q4.z * ea23.x + q4.w * ea23.y;
    p = dpp_add<0xB1>(p);
    p = dpp_add<0x4E>(p);
    float wgt = valid ? exp2f(p + u_n + w4v) : 0.f;
    s += wgt;
    ax0 += wgt * xv.x; ax1 += wgt * xv.y; ax2 += wgt * xv.z; ax3 += wgt * xv.w;
    ae0 += wgt * ea01.x; ae1 += wgt * ea01.y; ae2 += wgt * ea23.x; ae3 += wgt * ea23.y;
  }
  // reduce across the 4 edge-slots (row_ror keeps t4, cycles e')
  s   = dpp_add<0x124>(s);   s   = dpp_add<0x128>(s);
  ax0 = dpp_add<0x124>(ax0); ax0 = dpp_add<0x128>(ax0);
  ax1 = dpp_add<0x124>(ax1); ax1 = dpp_add<0x128>(ax1);
  ax2 = dpp_add<0x124>(ax2); ax2 = dpp_add<0x128>(ax2);
  ax3 = dpp_add<0x124>(ax3); ax3 = dpp_add<0x128>(ax3);
  ae0 = dpp_add<0x124>(ae0); ae0 = dpp_add<0x128>(ae0);
  ae1 = dpp_add<0x124>(ae1); ae1 = dpp_add<0x128>(ae1);
  ae2 = dpp_add<0x124>(ae2); ae2 = dpp_add<0x128>(ae2);
  ae3 = dpp_add<0x124>(ae3); ae3 = dpp_add<0x128>(ae3);

  float inv = (end > off) ? 1.f / s : 0.f;
  float dflag = (end > off) ? 1.f : 0.f;
  float an[4] = {ax0 * inv, ax1 * inv, ax2 * inv, ax3 * inv};
  float en[4] = {ae0 * inv, ae1 * inv, ae2 * inv, ae3 * inv};

  int t16 = lane & 15, base = h * 32 + t16, gb = lane & 48;
  float r0 = dflag * bv[base], r1 = dflag * bv[base + 16];
  const float4* wp = (const float4*)(P + P_WP) + lane * 16;
#pragma unroll
  for (int i = 0; i < 16; i++) {
    float axi = __shfl(an[i & 3], gb | (i >> 2));
    float aei = __shfl(en[i & 3], gb | (i >> 2));
    float4 w = wp[i];
    r0 += axi * w.z + aei * w.x;
    r1 += axi * w.w + aei * w.y;
  }
  // mean over heads
  r0 += __shfl_xor(r0, 16); r0 += __shfl_xor(r0, 32);
  r1 += __shfl_xor(r1, 16); r1 += __shfl_xor(r1, 32);

  // skip connection via packed Wskip
  const float4* xp = (const float4*)(x + n * 16);
  float4 X[4] = {xp[0], xp[1], xp[2], xp[3]};
  float sk0 = bskip[t16], sk1 = bskip[t16 + 16];
  const float4* wsp = (const float4*)(P + P_WSP) + t16 * 8;
#pragma unroll
  for (int k = 0; k < 8; k++) {
    float4 w = wsp[k];
    float xa = (k & 1) ? X[k >> 1].z : X[k >> 1].x;
    float xb = (k & 1) ? X[k >> 1].w : X[k >> 1].y;
    sk0 += xa * w.x + xb * w.z;
    sk1 += xa * w.y + xb * w.w;
  }
  float o0 = 0.25f * r0 + sk0;  // out[n][t16]
  float o1 = 0.25f * r1 + sk1;  // out[n][t16+16]

  // A[n][jj] / Cb[n][jj]
  int jj = lane & 31;
  float acc = (lane < 32) ? 0.f : b1[jj];
  const float4* w1p = (const float4*)(P + P_W1P) + lane * 8;
#pragma unroll
  for (int k = 0; k < 4; k++) {
    float4 w = w1p[k];
    acc += __shfl(o0, 4 * k) * w.x + __shfl(o0, 4 * k + 1) * w.y
         + __shfl(o0, 4 * k + 2) * w.z + __shfl(o0, 4 * k + 3) * w.w;
  }
#pragma unroll
  for (int k = 0; k < 4; k++) {
    float4 w = w1p[k + 4];
    acc += __shfl(o1, 4 * k) * w.x + __shfl(o1, 4 * k + 1) * w.y
         + __shfl(o1, 4 * k + 2) * w.z + __shfl(o1, 4 * k + 3) * w.w;
  }
  if (lane < 32) A[n * 32 + jj] = acc;
  else           Cb[n * 32 + jj] = acc;
}

// ---------------- Kernel 4: per-edge MLP, eid order --------------------
__global__ __launch_bounds__(256) void mlp_kernel(
    const int* __restrict__ ei, const float* __restrict__ edge_attr,
    const float* __restrict__ A, const float* __restrict__ Cb,
    const float* __restrict__ P, const float* __restrict__ W2,
    const float* __restrict__ b2v, float* __restrict__ out) {
  int e = blockIdx.x * 8 + (threadIdx.x >> 5);
  int l = threadIdx.x & 31;
  unsigned src = (unsigned)ei[e], dst = (unsigned)ei[NE + e];
  float hsum = A[src * 32u + l] + Cb[dst * 32u + l];
  const float4* eap = (const float4*)(edge_attr + (size_t)e * 16);
  const float4* wep = (const float4*)(P + P_W1EP) + l * 4;
#pragma unroll
  for (int k = 0; k < 4; k++) {
    float4 E = eap[k];
    float4 w = wep[k];
    hsum += E.x * w.x + E.y * w.y + E.z * w.z + E.w * w.w;
  }
  float hv = fmaxf(hsum, 0.f) * W2[l];
  hv += __shfl_xor(hv, 1); hv += __shfl_xor(hv, 2);
  hv += __shfl_xor(hv, 4); hv += __shfl_xor(hv, 8);
  hv += __shfl_xor(hv, 16);
  if (l == 0) out[e] = hv + b2v[0];
}

// ---------------- launch -----------------------------------------------
extern "C" void kernel_launch(void* const* d_in, const int* in_sizes, int n_in,
                              void* d_out, int out_size, void* d_ws, size_t ws_size,
                              hipStream_t stream) {
  const float* x         = (const float*)d_in[0];
  const int*   ei        = (const int*)d_in[1];
  const float* edge_attr = (const float*)d_in[2];
  const float* Wq = (const float*)d_in[3],  *bq = (const float*)d_in[4];
  const float* Wk = (const float*)d_in[5],  *bk = (const float*)d_in[6];
  const float* Wv = (const float*)d_in[7],  *bv = (const float*)d_in[8];
  const float* We = (const float*)d_in[9];
  const float* Wskip = (const float*)d_in[10], *bskip = (const float*)d_in[11];
  const float* W1 = (const float*)d_in[12], *b1 = (const float*)d_in[13];
  const float* W2 = (const float*)d_in[14], *b2 = (const float*)d_in[15];
  float* out = (float*)d_out;

  // workspace layout (16B-aligned blocks first)
  char* w = (char*)d_ws;
  float*   y    = (float*)w;            w += (size_t)NN * 64 * 4;   // 12.8 MB
  float*   qe   = (float*)w;            w += (size_t)NN * 64 * 4;   // 12.8 MB
  float*   u4   = (float*)w;            w += (size_t)NN * 4 * 4;    // 0.8 MB
  float*   w4   = (float*)w;            w += (size_t)NN * 4 * 4;    // 0.8 MB
  float*   A    = (float*)w;            w += (size_t)NN * 32 * 4;   // 6.4 MB
  float*   Cb   = (float*)w;            w += (size_t)NN * 32 * 4;   // 6.4 MB
  int*     s_src = (int*)w;             w += (size_t)NE * 4;        // 3.2 MB
  int*     s_eid = (int*)w;             w += (size_t)NE * 4;        // 3.2 MB
  int2*    s_tmp = (int2*)w;            w += (size_t)NE * 8;        // 6.4 MB
  __half*  s_ea = (__half*)w;           w += (size_t)NE * 16 * 2;   // 25.6 MB
  int*     hist_all = (int*)w;          w += (size_t)256 * 256 * 4; // 256 KB
  float*   P    = (float*)w;            w += (size_t)P_TOTAL * 4;   // 32.8 KB
  int*     btot = (int*)w;              w += 256 * 4;
  int*     coarse_offs = (int*)w;       w += 256 * 4;
  int*     offs = (int*)w;              w += ((size_t)NN + 1) * 4;

  precompute_kernel<<<1, 256, 0, stream>>>(Wq, Wk, bq, bk, We, Wv, Wskip, W1, P);
  node_linear_kernel<<<NODE_BLOCKS + 256, 256, 0, stream>>>(
      x, Wq, bq, Wk, bk, We, P, ei, hist_all, y, qe, u4, w4);
  scan_buckets_kernel<<<49, 256, 0, stream>>>(hist_all, btot);
  tiny_scan_kernel<<<1, 256, 0, stream>>>(btot, coarse_offs);
  bucket_scatter_kernel<<<256, 256, 0, stream>>>(ei, hist_all, coarse_offs, s_tmp);
  fine_csr_kernel<<<NB, 256, 0, stream>>>(s_tmp, coarse_offs, s_src, s_eid, offs);
  perm_ea_kernel<<<NE / 64, 256, 0, stream>>>(s_eid, edge_attr, s_ea);
  aggregate_kernel<<<NN / 4, 256, 0, stream>>>(y, qe, u4, w4, x, s_ea, s_src,
                                               offs, bv, bskip, b1, P, A, Cb);
  mlp_kernel<<<NE / 8, 256, 0, stream>>>(ei, edge_attr, A, Cb, P, W2, b2, out);
}

// Round 8
// 326.997 us; speedup vs baseline: 1.5289x; 1.5289x over previous
//
#include <hip/hip_runtime.h>

#define NN 50000
#define NE 800000
// IN_C=16, EDGE_IN=16, HID=32, HEADS=4, HC=128
#define NB 196            // coarse buckets = ceil(NN/256)
#define EPB 3125          // edges per bucket-build block (NE/256)
#define NODE_BLOCKS 12500 // NN/4

// scale folded into all alpha components: log2(e)/sqrt(32)
#define SL 0.25506413f

// ---------------- Kernel 0: weight precompute --------------------------
// Mbuf[h*256 + i*16 + j] = SL * sum_c Wq[i][h*32+c]*Wk[j][h*32+c]
// Mbuf[1024+h] = SL * bq_h . bk_h
__global__ __launch_bounds__(256) void precompute_kernel(
    const float* __restrict__ Wq, const float* __restrict__ Wk,
    const float* __restrict__ bq, const float* __restrict__ bk,
    float* __restrict__ Mbuf) {
  int t = threadIdx.x;
  for (int idx = t; idx < 1024; idx += 256) {
    int h = idx >> 8, i = (idx >> 4) & 15, j = idx & 15;
    float acc = 0.f;
#pragma unroll
    for (int c = 0; c < 32; c++)
      acc += Wq[i * 128 + h * 32 + c] * Wk[j * 128 + h * 32 + c];
    Mbuf[idx] = acc * SL;
  }
  if (t < 4) {
    float acc = 0.f;
#pragma unroll
    for (int c = 0; c < 32; c++) acc += bq[t * 32 + c] * bk[t * 32 + c];
    Mbuf[1024 + t] = acc * SL;
  }
}

// ---------------- Kernel 1: node precompute + coarse hist (fused) ------
__global__ __launch_bounds__(256) void node_linear_kernel(
    const float* __restrict__ x,
    const float* __restrict__ Wq, const float* __restrict__ bq,
    const float* __restrict__ Wk, const float* __restrict__ bk,
    const float* __restrict__ We, const float* __restrict__ Mbuf,
    const int* __restrict__ ei, int* __restrict__ hist_all,
    float* __restrict__ y, float* __restrict__ qe,
    float* __restrict__ u4, float* __restrict__ w4) {
  __shared__ int hist[NB];
  if (blockIdx.x >= NODE_BLOCKS) {
    int b = blockIdx.x - NODE_BLOCKS;  // [0,256)
    int t = threadIdx.x;
    if (t < NB) hist[t] = 0;
    __syncthreads();
    int base = b * EPB;
    for (int i = t; i < EPB; i += 256)
      atomicAdd(&hist[ei[NE + base + i] >> 8], 1);
    __syncthreads();
    if (t < NB) hist_all[t * 256 + b] = hist[t];
    return;
  }
  int wave = threadIdx.x >> 6;
  int lane = threadIdx.x & 63;
  int n = blockIdx.x * 4 + wave;
  int h = lane >> 4, t = lane & 15, base = h * 32 + t;
  int gb = lane & 48;

  float xr[16];
#pragma unroll
  for (int i = 0; i < 16; i++) xr[i] = x[n * 16 + i];

  float bqb = bq[base], bq16 = bq[base + 16];
  float bkb = bk[base], bk16 = bk[base + 16];
  float qb = bqb, q16 = bq16;
  float kb = bkb, k16 = bk16;
#pragma unroll
  for (int i = 0; i < 16; i++) {
    qb  += xr[i] * Wq[i * 128 + base];
    q16 += xr[i] * Wq[i * 128 + base + 16];
    kb  += xr[i] * Wk[i * 128 + base];
    k16 += xr[i] * Wk[i * 128 + base + 16];
  }

  // y_ht = sum_i x_i * M[h][i][t]  (M pre-scaled by SL)
  float yt = 0.f;
#pragma unroll
  for (int i = 0; i < 16; i++) yt += xr[i] * Mbuf[h * 256 + i * 16 + t];
  y[n * 64 + lane] = yt;

  // qe[h][t] = SL * sum_c q[h*32+c] * We[t*128 + h*32 + c]
  float acc = 0.f;
#pragma unroll
  for (int i = 0; i < 16; i++) {
    float qv  = __shfl(qb,  gb | i);
    float qv2 = __shfl(q16, gb | i);
    acc += qv * We[t * 128 + h * 32 + i] + qv2 * We[t * 128 + h * 32 + 16 + i];
  }
  qe[n * 64 + lane] = acc * SL;

  // u_h = SL*(q_h . bk_h) - SL*(bq_h . bk_h);  w_h = SL*(bq_h . k_h)
  float pu = qb * bkb + q16 * bk16;
  float pw = bqb * kb + bq16 * k16;
  pu += __shfl_xor(pu, 1); pw += __shfl_xor(pw, 1);
  pu += __shfl_xor(pu, 2); pw += __shfl_xor(pw, 2);
  pu += __shfl_xor(pu, 4); pw += __shfl_xor(pw, 4);
  pu += __shfl_xor(pu, 8); pw += __shfl_xor(pw, 8);
  if (t == 0) {
    u4[n * 4 + h] = pu * SL - Mbuf[1024 + h];
    w4[n * 4 + h] = pw * SL;
  }
}

// ---------------- CSR build ---------------------------------------------
__global__ __launch_bounds__(256) void scan_buckets_kernel(
    int* __restrict__ hist_all, int* __restrict__ btot) {
  int wv = blockIdx.x * 4 + (threadIdx.x >> 6);
  int l = threadIdx.x & 63;
  if (wv >= NB) return;
  int base = wv * 256;
  int run = 0;
#pragma unroll
  for (int c = 0; c < 4; c++) {
    int v = hist_all[base + c * 64 + l];
    int orig = v;
#pragma unroll
    for (int d = 1; d < 64; d <<= 1) {
      int u = __shfl_up(v, d);
      if (l >= d) v += u;
    }
    hist_all[base + c * 64 + l] = run + v - orig;
    run += __shfl(v, 63);
  }
  if (l == 0) btot[wv] = run;
}

__global__ __launch_bounds__(256) void tiny_scan_kernel(
    const int* __restrict__ btot, int* __restrict__ coarse_offs) {
  __shared__ int sc[256];
  int t = threadIdx.x;
  int v = (t < NB) ? btot[t] : 0;
  sc[t] = v;
  __syncthreads();
  for (int d = 1; d < 256; d <<= 1) {
    int u = (t >= d) ? sc[t - d] : 0;
    __syncthreads();
    sc[t] += u;
    __syncthreads();
  }
  if (t < NB) coarse_offs[t] = sc[t] - v;
  if (t == NB - 1) coarse_offs[NB] = sc[t];
}

__global__ __launch_bounds__(256) void bucket_scatter_kernel(
    const int* __restrict__ ei, const int* __restrict__ cursor_all,
    const int* __restrict__ coarse_offs, int2* __restrict__ s_tmp) {
  __shared__ int cur[NB];
  int t = threadIdx.x, b = blockIdx.x;
  if (t < NB) cur[t] = cursor_all[t * 256 + b] + coarse_offs[t];
  __syncthreads();
  int base = b * EPB;
  for (int i = t; i < EPB; i += 256) {
    int e = base + i;
    int src = ei[e], dst = ei[NE + e];
    int pos = atomicAdd(&cur[dst >> 8], 1);
    s_tmp[pos] = make_int2(src | ((dst & 255) << 16), e);
  }
}

__global__ __launch_bounds__(256) void fine_csr_kernel(
    const int2* __restrict__ s_tmp, const int* __restrict__ coarse_offs,
    int2* __restrict__ s_se, int* __restrict__ offs) {
  __shared__ int cnt[256], sc[256], cur[256];
  int t = threadIdx.x, b = blockIdx.x;
  int lo = coarse_offs[b], hi = coarse_offs[b + 1];
  cnt[t] = 0;
  __syncthreads();
  for (int p = lo + t; p < hi; p += 256)
    atomicAdd(&cnt[(s_tmp[p].x >> 16) & 255], 1);
  __syncthreads();
  int myc = cnt[t];
  sc[t] = myc;
  __syncthreads();
  for (int d = 1; d < 256; d <<= 1) {
    int v = (t >= d) ? sc[t - d] : 0;
    __syncthreads();
    sc[t] += v;
    __syncthreads();
  }
  int excl = sc[t] - myc;
  cur[t] = lo + excl;
  int gd = b * 256 + t;
  if (gd <= NN) offs[gd] = lo + excl;
  __syncthreads();
  for (int p = lo + t; p < hi; p += 256) {
    int2 w = s_tmp[p];
    int pos = atomicAdd(&cur[(w.x >> 16) & 255], 1);
    s_se[pos] = make_int2(w.x & 0xFFFF, w.y);
  }
}

// ---------------- Kernel 3: aggregation + A/C epilogue -----------------
// one wave per dst node; lane = (h, el): each lane owns ONE edge for ONE
// head -> lane-local 32-FMA dot, NO cross-lane ops in the loop, 16 edges
// in flight. Per-(h,t) sums recovered via wave-private LDS transpose.
#define RSTRIDE 36  // floats per lane slot (144 B, 16B-aligned)
__global__ __launch_bounds__(256) void aggregate_kernel(
    const float* __restrict__ y, const float* __restrict__ qe,
    const float* __restrict__ u4, const float* __restrict__ w4,
    const float* __restrict__ x, const float* __restrict__ edge_attr,
    const float* __restrict__ We, const float* __restrict__ Wv,
    const float* __restrict__ bv,
    const float* __restrict__ Wskip, const float* __restrict__ bskip,
    const float* __restrict__ W1, const float* __restrict__ b1,
    const int* __restrict__ offs, const int2* __restrict__ s_se,
    float* __restrict__ A, float* __restrict__ Cb) {
  __shared__ float red[4][64 * RSTRIDE + 32];
  int wave = threadIdx.x >> 6, lane = threadIdx.x & 63;
  int n = blockIdx.x * 4 + wave;
  if (n >= NN) return;
  int h = lane >> 4, el = lane & 15;

  const float4* yp = (const float4*)(y + n * 64 + h * 16);
  float4 y0 = yp[0], y1 = yp[1], y2 = yp[2], y3 = yp[3];
  const float4* qp = (const float4*)(qe + n * 64 + h * 16);
  float4 q0 = qp[0], q1 = qp[1], q2 = qp[2], q3 = qp[3];
  float u_n = u4[n * 4 + h];
  int off = offs[n], end = offs[n + 1];

  float s = 0.f;
  float4 ax0 = {0, 0, 0, 0}, ax1 = ax0, ax2 = ax0, ax3 = ax0;
  float4 ae0 = ax0, ae1 = ax0, ae2 = ax0, ae3 = ax0;

  for (int j = off; j < end; j += 16) {
    int idx = j + el;
    bool valid = idx < end;
    int jc = valid ? idx : off;
    int2 se = s_se[jc];
    const float4* xp = (const float4*)(x + (size_t)se.x * 16);
    float4 xv0 = xp[0], xv1 = xp[1], xv2 = xp[2], xv3 = xp[3];
    const float4* ep = (const float4*)(edge_attr + (size_t)se.y * 16);
    float4 ev0 = ep[0], ev1 = ep[1], ev2 = ep[2], ev3 = ep[3];
    float wsrc = w4[se.x * 4 + h];
    float p = u_n + wsrc;
    p += y0.x * xv0.x + y0.y * xv0.y + y0.z * xv0.z + y0.w * xv0.w;
    p += y1.x * xv1.x + y1.y * xv1.y + y1.z * xv1.z + y1.w * xv1.w;
    p += y2.x * xv2.x + y2.y * xv2.y + y2.z * xv2.z + y2.w * xv2.w;
    p += y3.x * xv3.x + y3.y * xv3.y + y3.z * xv3.z + y3.w * xv3.w;
    p += q0.x * ev0.x + q0.y * ev0.y + q0.z * ev0.z + q0.w * ev0.w;
    p += q1.x * ev1.x + q1.y * ev1.y + q1.z * ev1.z + q1.w * ev1.w;
    p += q2.x * ev2.x + q2.y * ev2.y + q2.z * ev2.z + q2.w * ev2.w;
    p += q3.x * ev3.x + q3.y * ev3.y + q3.z * ev3.z + q3.w * ev3.w;
    float wgt = valid ? exp2f(p) : 0.f;
    s += wgt;
    ax0.x += wgt * xv0.x; ax0.y += wgt * xv0.y; ax0.z += wgt * xv0.z; ax0.w += wgt * xv0.w;
    ax1.x += wgt * xv1.x; ax1.y += wgt * xv1.y; ax1.z += wgt * xv1.z; ax1.w += wgt * xv1.w;
    ax2.x += wgt * xv2.x; ax2.y += wgt * xv2.y; ax2.z += wgt * xv2.z; ax2.w += wgt * xv2.w;
    ax3.x += wgt * xv3.x; ax3.y += wgt * xv3.y; ax3.z += wgt * xv3.z; ax3.w += wgt * xv3.w;
    ae0.x += wgt * ev0.x; ae0.y += wgt * ev0.y; ae0.z += wgt * ev0.z; ae0.w += wgt * ev0.w;
    ae1.x += wgt * ev1.x; ae1.y += wgt * ev1.y; ae1.z += wgt * ev1.z; ae1.w += wgt * ev1.w;
    ae2.x += wgt * ev2.x; ae2.y += wgt * ev2.y; ae2.z += wgt * ev2.z; ae2.w += wgt * ev2.w;
    ae3.x += wgt * ev3.x; ae3.y += wgt * ev3.y; ae3.z += wgt * ev3.z; ae3.w += wgt * ev3.w;
  }

  // wave-private LDS transpose-reduce: slot base has +h*8 float skew (2-way banks)
  float* basep = &red[wave][(h * 16 + el) * RSTRIDE + h * 8];
  ((float4*)basep)[0] = ax0; ((float4*)basep)[1] = ax1;
  ((float4*)basep)[2] = ax2; ((float4*)basep)[3] = ax3;
  ((float4*)(basep + 16))[0] = ae0; ((float4*)(basep + 16))[1] = ae1;
  ((float4*)(basep + 16))[2] = ae2; ((float4*)(basep + 16))[3] = ae3;
  basep[32] = s;
  // same-wave RAW through LDS: compiler inserts lgkmcnt waits; no barrier needed

  int t16 = lane & 15;
  float S = 0.f, AX = 0.f, AE = 0.f;
#pragma unroll
  for (int e2 = 0; e2 < 16; e2++) {
    const float* b2 = &red[wave][(h * 16 + e2) * RSTRIDE + h * 8];
    AX += b2[t16];
    AE += b2[16 + t16];
    S  += b2[32];
  }

  float inv = (end > off) ? 1.f / S : 0.f;
  float dflag = (end > off) ? 1.f : 0.f;
  float axn = AX * inv, aen = AE * inv;
  int base = h * 32 + t16, gb = lane & 48;
  float r0 = dflag * bv[base], r1 = dflag * bv[base + 16];
#pragma unroll
  for (int i = 0; i < 16; i++) {
    float axi = __shfl(axn, gb | i);
    float aei = __shfl(aen, gb | i);
    r0 += axi * Wv[i * 128 + base]      + aei * We[i * 128 + base];
    r1 += axi * Wv[i * 128 + base + 16] + aei * We[i * 128 + base + 16];
  }
  // mean over heads
  r0 += __shfl_xor(r0, 16); r0 += __shfl_xor(r0, 32);
  r1 += __shfl_xor(r1, 16); r1 += __shfl_xor(r1, 32);

  // skip connection
  float sk0 = bskip[t16], sk1 = bskip[t16 + 16];
#pragma unroll
  for (int i = 0; i < 16; i++) {
    float xi = x[n * 16 + i];
    sk0 += xi * Wskip[i * 32 + t16];
    sk1 += xi * Wskip[i * 32 + t16 + 16];
  }
  float o0 = 0.25f * r0 + sk0;  // out[n][t16]
  float o1 = 0.25f * r1 + sk1;  // out[n][t16+16]

  // A[n][jj] = out@W1[0:32]; Cb[n][jj] = out@W1[48:80] + b1
  int jj = lane & 31;
  int roff = (lane < 32) ? 0 : 48;
  float acc = (lane < 32) ? 0.f : b1[jj];
#pragma unroll
  for (int i = 0; i < 16; i++) {
    float oi = __shfl(o0, i);
    acc += oi * W1[(roff + i) * 32 + jj];
  }
#pragma unroll
  for (int i = 0; i < 16; i++) {
    float oi = __shfl(o1, i);
    acc += oi * W1[(roff + 16 + i) * 32 + jj];
  }
  if (lane < 32) A[n * 32 + jj] = acc;
  else           Cb[n * 32 + jj] = acc;
}

// ---------------- Kernel 4: per-edge MLP, eid order --------------------
__global__ __launch_bounds__(256) void mlp_kernel(
    const int* __restrict__ ei, const float* __restrict__ edge_attr,
    const float* __restrict__ A, const float* __restrict__ Cb,
    const float* __restrict__ W1, const float* __restrict__ W2,
    const float* __restrict__ b2v, float* __restrict__ out) {
  int e = blockIdx.x * 8 + (threadIdx.x >> 5);
  int l = threadIdx.x & 31;
  unsigned src = (unsigned)ei[e], dst = (unsigned)ei[NE + e];
  float hsum = A[src * 32u + l] + Cb[dst * 32u + l];
  float eav = edge_attr[(unsigned)e * 16u + (l & 15)];
#pragma unroll
  for (int i = 0; i < 16; i++) {
    float ev = __shfl(eav, i, 32);
    hsum += ev * W1[(32 + i) * 32 + l];
  }
  float hv = fmaxf(hsum, 0.f) * W2[l];
  hv += __shfl_xor(hv, 1); hv += __shfl_xor(hv, 2);
  hv += __shfl_xor(hv, 4); hv += __shfl_xor(hv, 8);
  hv += __shfl_xor(hv, 16);
  if (l == 0) out[e] = hv + b2v[0];
}

// ---------------- launch -----------------------------------------------
extern "C" void kernel_launch(void* const* d_in, const int* in_sizes, int n_in,
                              void* d_out, int out_size, void* d_ws, size_t ws_size,
                              hipStream_t stream) {
  const float* x         = (const float*)d_in[0];
  const int*   ei        = (const int*)d_in[1];
  const float* edge_attr = (const float*)d_in[2];
  const float* Wq = (const float*)d_in[3],  *bq = (const float*)d_in[4];
  const float* Wk = (const float*)d_in[5],  *bk = (const float*)d_in[6];
  const float* Wv = (const float*)d_in[7],  *bv = (const float*)d_in[8];
  const float* We = (const float*)d_in[9];
  const float* Wskip = (const float*)d_in[10], *bskip = (const float*)d_in[11];
  const float* W1 = (const float*)d_in[12], *b1 = (const float*)d_in[13];
  const float* W2 = (const float*)d_in[14], *b2 = (const float*)d_in[15];
  float* out = (float*)d_out;

  // workspace layout
  char* w = (char*)d_ws;
  float*   y    = (float*)w;            w += (size_t)NN * 64 * 4;   // 12.8 MB
  float*   qe   = (float*)w;            w += (size_t)NN * 64 * 4;   // 12.8 MB
  float*   u4   = (float*)w;            w += (size_t)NN * 4 * 4;    // 0.8 MB
  float*   w4   = (float*)w;            w += (size_t)NN * 4 * 4;    // 0.8 MB
  float*   A    = (float*)w;            w += (size_t)NN * 32 * 4;   // 6.4 MB
  float*   Cb   = (float*)w;            w += (size_t)NN * 32 * 4;   // 6.4 MB
  int2*    s_se = (int2*)w;             w += (size_t)NE * 8;        // 6.4 MB
  int2*    s_tmp = (int2*)w;            w += (size_t)NE * 8;        // 6.4 MB
  int*     hist_all = (int*)w;          w += (size_t)256 * 256 * 4; // 256 KB
  int*     btot = (int*)w;              w += 256 * 4;
  int*     coarse_offs = (int*)w;       w += 256 * 4;
  int*     offs = (int*)w;              w += ((size_t)NN + 1) * 4;
  float*   Mbuf = (float*)w;            w += 1056 * 4;

  precompute_kernel<<<1, 256, 0, stream>>>(Wq, Wk, bq, bk, Mbuf);
  node_linear_kernel<<<NODE_BLOCKS + 256, 256, 0, stream>>>(
      x, Wq, bq, Wk, bk, We, Mbuf, ei, hist_all, y, qe, u4, w4);
  scan_buckets_kernel<<<49, 256, 0, stream>>>(hist_all, btot);
  tiny_scan_kernel<<<1, 256, 0, stream>>>(btot, coarse_offs);
  bucket_scatter_kernel<<<256, 256, 0, stream>>>(ei, hist_all, coarse_offs, s_tmp);
  fine_csr_kernel<<<NB, 256, 0, stream>>>(s_tmp, coarse_offs, s_se, offs);
  aggregate_kernel<<<NN / 4, 256, 0, stream>>>(y, qe, u4, w4, x, edge_attr,
                                               We, Wv, bv, Wskip, bskip, W1, b1,
                                               offs, s_se, A, Cb);
  mlp_kernel<<<NE / 8, 256, 0, stream>>>(ei, edge_attr, A, Cb, W1, W2, b2, out);
}